// Round 7
// baseline (1265.031 us; speedup 1.0000x reference)
//
#include <hip/hip_runtime.h>
#include <math.h>

// Problem constants (B, L, H, D, EF) = (2, 2048, 16, 64, 4)
#define L_SEQ 2048
#define NB 2
#define NH 16
#define HID 1024
#define QKVP 7168   // HID * 7
#define VP 5120     // HID * 5
#define NROWS 4096  // NB * L_SEQ
#define LN_EPS 1e-5f

typedef unsigned short u16;
using s16x4 = __attribute__((ext_vector_type(4))) short;
using s16x8 = __attribute__((ext_vector_type(8))) short;
using f32x4 = __attribute__((ext_vector_type(4))) float;

// --------------------------- bf16 split helpers ----------------------------
__device__ __forceinline__ u16 f2bf(float f) {  // RNE
  unsigned u = __float_as_uint(f);
  u += 0x7FFFu + ((u >> 16) & 1u);
  return (u16)(u >> 16);
}
__device__ __forceinline__ float bf2f(u16 h) {
  return __uint_as_float((unsigned)h << 16);
}
struct HiLo { short hi, lo; };
__device__ __forceinline__ HiLo split2(float x) {
  HiLo r;
  const u16 h = f2bf(x);
  r.hi = (short)h;
  r.lo = (short)f2bf(x - bf2f(h));
  return r;
}
__device__ __forceinline__ void split4(float4 v, s16x4& h4, s16x4& l4) {
  const HiLo a = split2(v.x), b = split2(v.y), c = split2(v.z), d = split2(v.w);
  h4[0] = a.hi; l4[0] = a.lo;
  h4[1] = b.hi; l4[1] = b.lo;
  h4[2] = c.hi; l4[2] = c.lo;
  h4[3] = d.hi; l4[3] = d.lo;
}

// ---------------------------------------------------------------------------
// Block-wide (256-thread) sum reduction. Returns full sum to every thread.
__device__ __forceinline__ float blk_sum256(float v, float* sm) {
#pragma unroll
  for (int m = 32; m >= 1; m >>= 1) v += __shfl_xor(v, m, 64);
  __syncthreads();
  if ((threadIdx.x & 63) == 0) sm[threadIdx.x >> 6] = v;
  __syncthreads();
  return sm[0] + sm[1] + sm[2] + sm[3];
}

// ---------------------------------------------------------------------------
// Kernel 1: input LayerNorm over HID, then channel-group seq-shift (scatter),
// fp32 out. Zero-fills shift boundary rows (dest is poisoned, must init).
__global__ __launch_bounds__(256) void ln_shift_kernel(
    const float* __restrict__ x, const float* __restrict__ g,
    const float* __restrict__ bb, float* __restrict__ xs) {
  __shared__ float sm[4];
  const int row = blockIdx.x;  // b*L + l
  const int l = row & (L_SEQ - 1);
  const int t = threadIdx.x;
  const float4 v = reinterpret_cast<const float4*>(x + (size_t)row * HID)[t];
  float s = v.x + v.y + v.z + v.w;
  const float mean = blk_sum256(s, sm) * (1.0f / HID);
  const float dx = v.x - mean, dy = v.y - mean, dz = v.z - mean, dw = v.w - mean;
  const float sq = dx * dx + dy * dy + dz * dz + dw * dw;
  const float var = blk_sum256(sq, sm) * (1.0f / HID);
  const float rstd = rsqrtf(var + LN_EPS);
  const float4 gv = reinterpret_cast<const float4*>(g)[t];
  const float4 bv = reinterpret_cast<const float4*>(bb)[t];
  float4 n;
  n.x = dx * rstd * gv.x + bv.x;
  n.y = dy * rstd * gv.y + bv.y;
  n.z = dz * rstd * gv.z + bv.z;
  n.w = dw * rstd * gv.w + bv.w;
  const int c0 = t * 4;
  const float4 zero = make_float4(0.f, 0.f, 0.f, 0.f);
  if (c0 < 128) {
    if (l + 1 < L_SEQ) reinterpret_cast<float4*>(xs + (size_t)(row + 1) * HID)[t] = n;
    if (l == 0)        reinterpret_cast<float4*>(xs + (size_t)row * HID)[t] = zero;
  } else if (c0 < 256) {
    if (l + 3 < L_SEQ) reinterpret_cast<float4*>(xs + (size_t)(row + 3) * HID)[t] = n;
    if (l < 3)         reinterpret_cast<float4*>(xs + (size_t)row * HID)[t] = zero;
  } else {
    reinterpret_cast<float4*>(xs + (size_t)row * HID)[t] = n;
  }
}

// ---------------------------------------------------------------------------
// Split-bf16 NT GEMM via MFMA, fp32 operands in global memory:
//   C[m][n] = sum_k A[m][k] * Bw[n][k]
// Staging loads fp32 and splits to (bf16 hi, bf16 lo) in LDS. Per fragment
// pair: hi*hi + hi*lo + lo*hi (lo*lo dropped, ~2^-18 relative).
// Tile 128x128x32; 4 waves (2x2), each owns a 64x64 sub-tile of C.
// MFMA 16x16x32_bf16; A/B k-map assumption cancels (same bijection both
// operands, mirrored layouts -> any k-permutation applies to both -> sum
// invariant). LDS row stride 40 shorts = 80 B: 16B-aligned b128 writes,
// bounded read conflicts.
// A_REMAP (gemm2): A row is h's [o | pg] view — k>=1024 lives at col k+2048.
template <bool RELU, bool A_REMAP>
__global__ __launch_bounds__(256, 2) void gemm_f32_hilo(
    const float* __restrict__ A, const float* __restrict__ Bw,
    float* __restrict__ C, int N, int K, int lda, int nbx) {
  __shared__ __align__(16) u16 Ah[128][40];
  __shared__ __align__(16) u16 Al[128][40];
  __shared__ __align__(16) u16 Bh[128][40];
  __shared__ __align__(16) u16 Bl[128][40];

  // bijective XCD swizzle (gridDim.x % 8 == 0 at both call sites)
  const int cpx = (int)gridDim.x >> 3;
  const int b0 = blockIdx.x;
  const int swz = (b0 & 7) * cpx + (b0 >> 3);
  const int bx = swz % nbx, by = swz / nbx;
  const int m0 = by * 128, n0 = bx * 128;

  const int t = threadIdx.x;
  const int lane = t & 63, w = t >> 6;
  const int wr = (w >> 1) * 64, wc = (w & 1) * 64;  // wave sub-tile origin
  const int lrow = lane & 15;
  const int lkg = (lane >> 4) * 4;

  f32x4 acc[4][4] = {};

  const int sr = t >> 1;       // staging row 0..127
  const int sk = (t & 1) * 16; // staging k base {0,16}

  for (int k0 = 0; k0 < K; k0 += 32) {
    int ak = sk + k0;
    if (A_REMAP && ak >= 1024) ak += 2048;  // skip k,v slots of h
    const float* ap = A + (size_t)(m0 + sr) * lda + ak;
    const float* bp = Bw + (size_t)(n0 + sr) * K + sk + k0;
    const float4 av0 = *(const float4*)(ap);
    const float4 av1 = *(const float4*)(ap + 4);
    const float4 av2 = *(const float4*)(ap + 8);
    const float4 av3 = *(const float4*)(ap + 12);
    const float4 bv0 = *(const float4*)(bp);
    const float4 bv1 = *(const float4*)(bp + 4);
    const float4 bv2 = *(const float4*)(bp + 8);
    const float4 bv3 = *(const float4*)(bp + 12);
    __syncthreads();  // previous iteration done reading LDS
    {
      s16x4 h0, l0, h1, l1;
      split4(av0, h0, l0); split4(av1, h1, l1);
      *(s16x8*)&Ah[sr][sk] = __builtin_shufflevector(h0, h1, 0, 1, 2, 3, 4, 5, 6, 7);
      *(s16x8*)&Al[sr][sk] = __builtin_shufflevector(l0, l1, 0, 1, 2, 3, 4, 5, 6, 7);
      split4(av2, h0, l0); split4(av3, h1, l1);
      *(s16x8*)&Ah[sr][sk + 8] = __builtin_shufflevector(h0, h1, 0, 1, 2, 3, 4, 5, 6, 7);
      *(s16x8*)&Al[sr][sk + 8] = __builtin_shufflevector(l0, l1, 0, 1, 2, 3, 4, 5, 6, 7);
      split4(bv0, h0, l0); split4(bv1, h1, l1);
      *(s16x8*)&Bh[sr][sk] = __builtin_shufflevector(h0, h1, 0, 1, 2, 3, 4, 5, 6, 7);
      *(s16x8*)&Bl[sr][sk] = __builtin_shufflevector(l0, l1, 0, 1, 2, 3, 4, 5, 6, 7);
      split4(bv2, h0, l0); split4(bv3, h1, l1);
      *(s16x8*)&Bh[sr][sk + 8] = __builtin_shufflevector(h0, h1, 0, 1, 2, 3, 4, 5, 6, 7);
      *(s16x8*)&Bl[sr][sk + 8] = __builtin_shufflevector(l0, l1, 0, 1, 2, 3, 4, 5, 6, 7);
    }
    __syncthreads();  // tile ready

    s16x8 afh[4], afl[4], bfh[4], bfl[4];
#pragma unroll
    for (int f = 0; f < 4; ++f) {
      const int ar = wr + f * 16 + lrow;
      const int bc = wc + f * 16 + lrow;
      s16x4 p0, p1;
      p0 = *(const s16x4*)&Ah[ar][lkg]; p1 = *(const s16x4*)&Ah[ar][16 + lkg];
      afh[f] = __builtin_shufflevector(p0, p1, 0, 1, 2, 3, 4, 5, 6, 7);
      p0 = *(const s16x4*)&Al[ar][lkg]; p1 = *(const s16x4*)&Al[ar][16 + lkg];
      afl[f] = __builtin_shufflevector(p0, p1, 0, 1, 2, 3, 4, 5, 6, 7);
      p0 = *(const s16x4*)&Bh[bc][lkg]; p1 = *(const s16x4*)&Bh[bc][16 + lkg];
      bfh[f] = __builtin_shufflevector(p0, p1, 0, 1, 2, 3, 4, 5, 6, 7);
      p0 = *(const s16x4*)&Bl[bc][lkg]; p1 = *(const s16x4*)&Bl[bc][16 + lkg];
      bfl[f] = __builtin_shufflevector(p0, p1, 0, 1, 2, 3, 4, 5, 6, 7);
    }
#pragma unroll
    for (int i = 0; i < 4; ++i)
#pragma unroll
      for (int j = 0; j < 4; ++j) {
        acc[i][j] = __builtin_amdgcn_mfma_f32_16x16x32_bf16(afh[i], bfh[j], acc[i][j], 0, 0, 0);
        acc[i][j] = __builtin_amdgcn_mfma_f32_16x16x32_bf16(afh[i], bfl[j], acc[i][j], 0, 0, 0);
        acc[i][j] = __builtin_amdgcn_mfma_f32_16x16x32_bf16(afl[i], bfh[j], acc[i][j], 0, 0, 0);
      }
  }
  // Epilogue. D mapping (m89-verified): col = lane&15, row = 4*(lane>>4)+reg.
#pragma unroll
  for (int i = 0; i < 4; ++i) {
    const int row0 = m0 + wr + i * 16 + lkg;
#pragma unroll
    for (int j = 0; j < 4; ++j) {
      const int col = n0 + wc + j * 16 + lrow;
#pragma unroll
      for (int r = 0; r < 4; ++r) {
        float v = acc[i][j][r];
        if (RELU) v = fmaxf(v, 0.f);
        C[(size_t)(row0 + r) * N + col] = v;
      }
    }
  }
}

// ---------------------------------------------------------------------------
// Kernel 3: mid LayerNorm over QKVP=7168, in place on h. One block per row.
__global__ __launch_bounds__(256) void mid_ln_kernel(
    float* __restrict__ h, const float* __restrict__ g, const float* __restrict__ bb) {
  __shared__ float sm[4];
  const int row = blockIdx.x;
  const int t = threadIdx.x;
  float* hr = h + (size_t)row * QKVP;
  float4 r[7];
  float s = 0.f;
#pragma unroll
  for (int j = 0; j < 7; ++j) {
    r[j] = reinterpret_cast<float4*>(hr)[t + j * 256];
    s += r[j].x + r[j].y + r[j].z + r[j].w;
  }
  const float mean = blk_sum256(s, sm) * (1.0f / QKVP);
  float sq = 0.f;
#pragma unroll
  for (int j = 0; j < 7; ++j) {
    r[j].x -= mean; r[j].y -= mean; r[j].z -= mean; r[j].w -= mean;
    sq += r[j].x * r[j].x + r[j].y * r[j].y + r[j].z * r[j].z + r[j].w * r[j].w;
  }
  const float rstd = rsqrtf(blk_sum256(sq, sm) * (1.0f / QKVP) + LN_EPS);
#pragma unroll
  for (int j = 0; j < 7; ++j) {
    const float4 gv = reinterpret_cast<const float4*>(g)[t + j * 256];
    const float4 bv = reinterpret_cast<const float4*>(bb)[t + j * 256];
    float4 o;
    o.x = r[j].x * rstd * gv.x + bv.x;
    o.y = r[j].y * rstd * gv.y + bv.y;
    o.z = r[j].z * rstd * gv.z + bv.z;
    o.w = r[j].w * rstd * gv.w + bv.w;
    reinterpret_cast<float4*>(hr)[t + j * 256] = o;
  }
}

// ---------------------------------------------------------------------------
// Kernel 4: flash attention, fp32. Grid (L/64 q-tiles, B*H). 256 thr = 16x16.
// Writes O back into h's q-slot (cols [0,HID)): each block reads exactly the
// q-rectangle (rows i0..i0+63, cols hh*64..+63) that it alone later
// overwrites — read-before-write within the block, disjoint across blocks.
__global__ __launch_bounds__(256) void attn_kernel(
    float* __restrict__ h, const float* __restrict__ slopes) {
  __shared__ float Qs[64][68];
  __shared__ float KVs[64][68];
  __shared__ float Ps[64][68];
  const int it = blockIdx.x;
  const int bh = blockIdx.y;
  const int b = bh >> 4, hh = bh & 15;
  const float slope = slopes[hh];
  const int t = threadIdx.x, tx = t & 15, ty = t >> 4;
  const int i0 = it * 64;
  const size_t base = (size_t)b * L_SEQ * QKVP;

#pragma unroll
  for (int rr = 0; rr < 4; ++rr) {
    const int i = rr * 16 + ty;
    const int d0 = tx * 4;
    const float4 q = *reinterpret_cast<const float4*>(
        &h[base + (size_t)(i0 + i) * QKVP + hh * 64 + d0]);
    Qs[d0 + 0][i] = q.x; Qs[d0 + 1][i] = q.y; Qs[d0 + 2][i] = q.z; Qs[d0 + 3][i] = q.w;
  }

  float m_run[4], l_run[4], o[4][4];
#pragma unroll
  for (int r = 0; r < 4; ++r) {
    m_run[r] = -INFINITY; l_run[r] = 0.f;
#pragma unroll
    for (int c = 0; c < 4; ++c) o[r][c] = 0.f;
  }

  for (int jt = 0; jt <= it; ++jt) {
    const int j0 = jt * 64;
    __syncthreads();  // prev iter done with KVs(V), Ps (also covers Q load)
#pragma unroll
    for (int rr = 0; rr < 4; ++rr) {
      const int j = rr * 16 + ty;
      const float4 k = *reinterpret_cast<const float4*>(
          &h[base + (size_t)(j0 + j) * QKVP + HID + hh * 64 + tx * 4]);
      KVs[tx * 4 + 0][j] = k.x; KVs[tx * 4 + 1][j] = k.y;
      KVs[tx * 4 + 2][j] = k.z; KVs[tx * 4 + 3][j] = k.w;
    }
    __syncthreads();
    float s[4][4];
#pragma unroll
    for (int r = 0; r < 4; ++r)
#pragma unroll
      for (int c = 0; c < 4; ++c) s[r][c] = 0.f;
#pragma unroll 8
    for (int d = 0; d < 64; ++d) {
      const float4 qv = *reinterpret_cast<const float4*>(&Qs[d][ty * 4]);
      const float4 kv = *reinterpret_cast<const float4*>(&KVs[d][tx * 4]);
      const float qa[4] = {qv.x, qv.y, qv.z, qv.w};
      const float ka[4] = {kv.x, kv.y, kv.z, kv.w};
#pragma unroll
      for (int r = 0; r < 4; ++r)
#pragma unroll
        for (int c = 0; c < 4; ++c) s[r][c] += qa[r] * ka[c];
    }
#pragma unroll
    for (int r = 0; r < 4; ++r) {
      const int ig = i0 + ty * 4 + r;
#pragma unroll
      for (int c = 0; c < 4; ++c) {
        const int jg = j0 + tx * 4 + c;
        float v = s[r][c] * 0.125f + (float)jg * slope;
        if (jg > ig) v = -1e10f;
        s[r][c] = v;
      }
    }
    float pnew[4][4];
#pragma unroll
    for (int r = 0; r < 4; ++r) {
      float rowmax = fmaxf(fmaxf(s[r][0], s[r][1]), fmaxf(s[r][2], s[r][3]));
#pragma unroll
      for (int mm = 1; mm < 16; mm <<= 1) rowmax = fmaxf(rowmax, __shfl_xor(rowmax, mm, 64));
      const float m_new = fmaxf(m_run[r], rowmax);
      const float scale = __expf(m_run[r] - m_new);
      m_run[r] = m_new;
      float rs = 0.f;
#pragma unroll
      for (int c = 0; c < 4; ++c) {
        const float p = __expf(s[r][c] - m_new);
        pnew[r][c] = p;
        rs += p;
      }
#pragma unroll
      for (int mm = 1; mm < 16; mm <<= 1) rs += __shfl_xor(rs, mm, 64);
      l_run[r] = l_run[r] * scale + rs;
#pragma unroll
      for (int c = 0; c < 4; ++c) o[r][c] *= scale;
    }
    __syncthreads();  // done reading K from KVs
#pragma unroll
    for (int rr = 0; rr < 4; ++rr) {
      const int j = rr * 16 + ty;
      const float4 v = *reinterpret_cast<const float4*>(
          &h[base + (size_t)(j0 + j) * QKVP + 2 * HID + hh * 64 + tx * 4]);
      *reinterpret_cast<float4*>(&KVs[j][tx * 4]) = v;
    }
#pragma unroll
    for (int r = 0; r < 4; ++r)
#pragma unroll
      for (int c = 0; c < 4; ++c) Ps[tx * 4 + c][ty * 4 + r] = pnew[r][c];
    __syncthreads();
#pragma unroll 8
    for (int j = 0; j < 64; ++j) {
      const float4 pv = *reinterpret_cast<const float4*>(&Ps[j][ty * 4]);
      const float4 vv = *reinterpret_cast<const float4*>(&KVs[j][tx * 4]);
      const float pa[4] = {pv.x, pv.y, pv.z, pv.w};
      const float va[4] = {vv.x, vv.y, vv.z, vv.w};
#pragma unroll
      for (int r = 0; r < 4; ++r)
#pragma unroll
        for (int c = 0; c < 4; ++c) o[r][c] += pa[r] * va[c];
    }
  }
  // epilogue: normalize, write O into h's q-slot
#pragma unroll
  for (int r = 0; r < 4; ++r) {
    const float inv = 1.0f / l_run[r];
    float4 ov;
    ov.x = o[r][0] * inv; ov.y = o[r][1] * inv;
    ov.z = o[r][2] * inv; ov.w = o[r][3] * inv;
    *reinterpret_cast<float4*>(
        &h[base + (size_t)(i0 + ty * 4 + r) * QKVP + hh * 64 + tx * 4]) = ov;
  }
}

// ---------------------------------------------------------------------------
// Kernel 5: pg = gelu_exact(p) * roll(p, 1), IN PLACE over h's p-slot.
// One block per row; all reads (incl. the roll predecessor) before a
// barrier, all writes after — race-free in-place roll.
__device__ __forceinline__ float gelu_exact(float x) {
  return 0.5f * x * (1.0f + erff(x * 0.70710678118654752f));
}
__global__ __launch_bounds__(256) void pg_kernel(float* __restrict__ h) {
  const int row = blockIdx.x;
  float* p = h + (size_t)row * QKVP + 3 * HID;
  const int t = threadIdx.x;
  float4 v[4];
  float pm1[4];
#pragma unroll
  for (int j = 0; j < 4; ++j) {
    const int c4 = t + j * 256;  // 1024 float4 per row
    v[j] = reinterpret_cast<float4*>(p)[c4];
    pm1[j] = p[(c4 * 4 - 1) & 4095];
  }
  __syncthreads();
#pragma unroll
  for (int j = 0; j < 4; ++j) {
    const int c4 = t + j * 256;
    float4 o;
    o.x = gelu_exact(v[j].x) * pm1[j];
    o.y = gelu_exact(v[j].y) * v[j].x;
    o.z = gelu_exact(v[j].z) * v[j].y;
    o.w = gelu_exact(v[j].w) * v[j].z;
    reinterpret_cast<float4*>(p)[c4] = o;
  }
}

// ---------------------------------------------------------------------------
// Kernel 7: final LayerNorm over HID, in place on out.
__global__ __launch_bounds__(256) void ln1024_kernel(
    float* __restrict__ io, const float* __restrict__ g, const float* __restrict__ bb) {
  __shared__ float sm[4];
  const int row = blockIdx.x;
  const int t = threadIdx.x;
  float* xr = io + (size_t)row * HID;
  const float4 v = reinterpret_cast<const float4*>(xr)[t];
  float s = v.x + v.y + v.z + v.w;
  const float mean = blk_sum256(s, sm) * (1.0f / HID);
  const float dx = v.x - mean, dy = v.y - mean, dz = v.z - mean, dw = v.w - mean;
  const float sq = dx * dx + dy * dy + dz * dz + dw * dw;
  const float var = blk_sum256(sq, sm) * (1.0f / HID);
  const float rstd = rsqrtf(var + LN_EPS);
  const float4 gv = reinterpret_cast<const float4*>(g)[t];
  const float4 bv = reinterpret_cast<const float4*>(bb)[t];
  float4 n;
  n.x = dx * rstd * gv.x + bv.x;
  n.y = dy * rstd * gv.y + bv.y;
  n.z = dz * rstd * gv.z + bv.z;
  n.w = dw * rstd * gv.w + bv.w;
  reinterpret_cast<float4*>(xr)[t] = n;
}

// ---------------------------------------------------------------------------
extern "C" void kernel_launch(void* const* d_in, const int* in_sizes, int n_in,
                              void* d_out, int out_size, void* d_ws, size_t ws_size,
                              hipStream_t stream) {
  const float* x      = (const float*)d_in[0];
  const float* in_g   = (const float*)d_in[1];
  const float* in_b   = (const float*)d_in[2];
  const float* W_in   = (const float*)d_in[3];
  const float* mid_g  = (const float*)d_in[4];
  const float* mid_b  = (const float*)d_in[5];
  const float* slopes = (const float*)d_in[6];
  const float* W_out  = (const float*)d_in[7];
  const float* out_g  = (const float*)d_in[8];
  const float* out_b  = (const float*)d_in[9];
  float* out = (float*)d_out;

  // Workspace: h fp32 only = 117,440,512 B (112 MiB).
  // xs (4096x1024 fp32 = out_size) is staged IN d_out: written by ln_shift,
  // consumed by gemm1, dead until gemm2 overwrites d_out with the result.
  float* h  = (float*)d_ws;
  float* xs = out;
  const size_t needed = (size_t)NROWS * QKVP * sizeof(float);
  if (ws_size < needed) return;  // diagnostic: no crash; output stays poisoned

  ln_shift_kernel<<<NROWS, 256, 0, stream>>>(x, in_g, in_b, xs);
  // gemm1: h = relu(xs @ W_in^T)   [4096 x 7168, K=1024]
  gemm_f32_hilo<true, false><<<(NROWS / 128) * (QKVP / 128), 256, 0, stream>>>(
      xs, W_in, h, QKVP, HID, HID, QKVP / 128);
  mid_ln_kernel<<<NROWS, 256, 0, stream>>>(h, mid_g, mid_b);
  attn_kernel<<<dim3(L_SEQ / 64, NB * NH), 256, 0, stream>>>(h, slopes);
  pg_kernel<<<NROWS, 256, 0, stream>>>(h);
  // gemm2: out = [o | pg] @ W_out^T   [4096 x 1024, K=5120, A remapped in h]
  gemm_f32_hilo<false, true><<<(NROWS / 128) * (HID / 128), 256, 0, stream>>>(
      h, W_out, out, HID, VP, QKVP, HID / 128);
  ln1024_kernel<<<NROWS, 256, 0, stream>>>(out, out_g, out_b);
}

// Round 9
// 961.291 us; speedup vs baseline: 1.3160x; 1.3160x over previous
//
#include <hip/hip_runtime.h>
#include <math.h>

// Problem constants (B, L, H, D, EF) = (2, 2048, 16, 64, 4)
#define L_SEQ 2048
#define NB 2
#define NH 16
#define HID 1024
#define QKVP 7168   // HID * 7
#define VP 5120     // HID * 5
#define NROWS 4096  // NB * L_SEQ
#define LN_EPS 1e-5f

typedef unsigned short u16;
using s16x4 = __attribute__((ext_vector_type(4))) short;
using s16x8 = __attribute__((ext_vector_type(8))) short;
using f32x4 = __attribute__((ext_vector_type(4))) float;

// --------------------------- bf16 split helpers ----------------------------
__device__ __forceinline__ u16 f2bf(float f) {  // RNE
  unsigned u = __float_as_uint(f);
  u += 0x7FFFu + ((u >> 16) & 1u);
  return (u16)(u >> 16);
}
__device__ __forceinline__ float bf2f(u16 h) {
  return __uint_as_float((unsigned)h << 16);
}
struct HiLo { short hi, lo; };
__device__ __forceinline__ HiLo split2(float x) {
  HiLo r;
  const u16 h = f2bf(x);
  r.hi = (short)h;
  r.lo = (short)f2bf(x - bf2f(h));
  return r;
}
__device__ __forceinline__ void split4(float4 v, s16x4& h4, s16x4& l4) {
  const HiLo a = split2(v.x), b = split2(v.y), c = split2(v.z), d = split2(v.w);
  h4[0] = a.hi; l4[0] = a.lo;
  h4[1] = b.hi; l4[1] = b.lo;
  h4[2] = c.hi; l4[2] = c.lo;
  h4[3] = d.hi; l4[3] = d.lo;
}
__device__ __forceinline__ void split4v(f32x4 v, s16x4& h4, s16x4& l4) {
  const HiLo a = split2(v[0]), b = split2(v[1]), c = split2(v[2]), d = split2(v[3]);
  h4[0] = a.hi; l4[0] = a.lo;
  h4[1] = b.hi; l4[1] = b.lo;
  h4[2] = c.hi; l4[2] = c.lo;
  h4[3] = d.hi; l4[3] = d.lo;
}
__device__ __forceinline__ s16x8 shuf8(s16x4 a, s16x4 b) {
  return __builtin_shufflevector(a, b, 0, 1, 2, 3, 4, 5, 6, 7);
}

// ---------------------------------------------------------------------------
// Block-wide (256-thread) sum reduction. Returns full sum to every thread.
__device__ __forceinline__ float blk_sum256(float v, float* sm) {
#pragma unroll
  for (int m = 32; m >= 1; m >>= 1) v += __shfl_xor(v, m, 64);
  __syncthreads();
  if ((threadIdx.x & 63) == 0) sm[threadIdx.x >> 6] = v;
  __syncthreads();
  return sm[0] + sm[1] + sm[2] + sm[3];
}

// ---------------------------------------------------------------------------
// Kernel 1: input LayerNorm over HID, then channel-group seq-shift (scatter),
// fp32 out. Zero-fills shift boundary rows (dest is poisoned, must init).
__global__ __launch_bounds__(256) void ln_shift_kernel(
    const float* __restrict__ x, const float* __restrict__ g,
    const float* __restrict__ bb, float* __restrict__ xs) {
  __shared__ float sm[4];
  const int row = blockIdx.x;  // b*L + l
  const int l = row & (L_SEQ - 1);
  const int t = threadIdx.x;
  const float4 v = reinterpret_cast<const float4*>(x + (size_t)row * HID)[t];
  float s = v.x + v.y + v.z + v.w;
  const float mean = blk_sum256(s, sm) * (1.0f / HID);
  const float dx = v.x - mean, dy = v.y - mean, dz = v.z - mean, dw = v.w - mean;
  const float sq = dx * dx + dy * dy + dz * dz + dw * dw;
  const float var = blk_sum256(sq, sm) * (1.0f / HID);
  const float rstd = rsqrtf(var + LN_EPS);
  const float4 gv = reinterpret_cast<const float4*>(g)[t];
  const float4 bv = reinterpret_cast<const float4*>(bb)[t];
  float4 n;
  n.x = dx * rstd * gv.x + bv.x;
  n.y = dy * rstd * gv.y + bv.y;
  n.z = dz * rstd * gv.z + bv.z;
  n.w = dw * rstd * gv.w + bv.w;
  const int c0 = t * 4;
  const float4 zero = make_float4(0.f, 0.f, 0.f, 0.f);
  if (c0 < 128) {
    if (l + 1 < L_SEQ) reinterpret_cast<float4*>(xs + (size_t)(row + 1) * HID)[t] = n;
    if (l == 0)        reinterpret_cast<float4*>(xs + (size_t)row * HID)[t] = zero;
  } else if (c0 < 256) {
    if (l + 3 < L_SEQ) reinterpret_cast<float4*>(xs + (size_t)(row + 3) * HID)[t] = n;
    if (l < 3)         reinterpret_cast<float4*>(xs + (size_t)row * HID)[t] = zero;
  } else {
    reinterpret_cast<float4*>(xs + (size_t)row * HID)[t] = n;
  }
}

// ---------------------------------------------------------------------------
// Split-bf16 NT GEMM via MFMA, fp32 operands in global memory (unchanged,
// validated round 7: passed with absmax 1.6e-2).
template <bool RELU, bool A_REMAP>
__global__ __launch_bounds__(256, 2) void gemm_f32_hilo(
    const float* __restrict__ A, const float* __restrict__ Bw,
    float* __restrict__ C, int N, int K, int lda, int nbx) {
  __shared__ __align__(16) u16 Ah[128][40];
  __shared__ __align__(16) u16 Al[128][40];
  __shared__ __align__(16) u16 Bh[128][40];
  __shared__ __align__(16) u16 Bl[128][40];

  const int cpx = (int)gridDim.x >> 3;
  const int b0 = blockIdx.x;
  const int swz = (b0 & 7) * cpx + (b0 >> 3);
  const int bx = swz % nbx, by = swz / nbx;
  const int m0 = by * 128, n0 = bx * 128;

  const int t = threadIdx.x;
  const int lane = t & 63, w = t >> 6;
  const int wr = (w >> 1) * 64, wc = (w & 1) * 64;
  const int lrow = lane & 15;
  const int lkg = (lane >> 4) * 4;

  f32x4 acc[4][4] = {};

  const int sr = t >> 1;
  const int sk = (t & 1) * 16;

  for (int k0 = 0; k0 < K; k0 += 32) {
    int ak = sk + k0;
    if (A_REMAP && ak >= 1024) ak += 2048;  // skip k,v slots of h
    const float* ap = A + (size_t)(m0 + sr) * lda + ak;
    const float* bp = Bw + (size_t)(n0 + sr) * K + sk + k0;
    const float4 av0 = *(const float4*)(ap);
    const float4 av1 = *(const float4*)(ap + 4);
    const float4 av2 = *(const float4*)(ap + 8);
    const float4 av3 = *(const float4*)(ap + 12);
    const float4 bv0 = *(const float4*)(bp);
    const float4 bv1 = *(const float4*)(bp + 4);
    const float4 bv2 = *(const float4*)(bp + 8);
    const float4 bv3 = *(const float4*)(bp + 12);
    __syncthreads();
    {
      s16x4 h0, l0, h1, l1;
      split4(av0, h0, l0); split4(av1, h1, l1);
      *(s16x8*)&Ah[sr][sk] = shuf8(h0, h1);
      *(s16x8*)&Al[sr][sk] = shuf8(l0, l1);
      split4(av2, h0, l0); split4(av3, h1, l1);
      *(s16x8*)&Ah[sr][sk + 8] = shuf8(h0, h1);
      *(s16x8*)&Al[sr][sk + 8] = shuf8(l0, l1);
      split4(bv0, h0, l0); split4(bv1, h1, l1);
      *(s16x8*)&Bh[sr][sk] = shuf8(h0, h1);
      *(s16x8*)&Bl[sr][sk] = shuf8(l0, l1);
      split4(bv2, h0, l0); split4(bv3, h1, l1);
      *(s16x8*)&Bh[sr][sk + 8] = shuf8(h0, h1);
      *(s16x8*)&Bl[sr][sk + 8] = shuf8(l0, l1);
    }
    __syncthreads();

    s16x8 afh[4], afl[4], bfh[4], bfl[4];
#pragma unroll
    for (int f = 0; f < 4; ++f) {
      const int ar = wr + f * 16 + lrow;
      const int bc = wc + f * 16 + lrow;
      s16x4 p0, p1;
      p0 = *(const s16x4*)&Ah[ar][lkg]; p1 = *(const s16x4*)&Ah[ar][16 + lkg];
      afh[f] = shuf8(p0, p1);
      p0 = *(const s16x4*)&Al[ar][lkg]; p1 = *(const s16x4*)&Al[ar][16 + lkg];
      afl[f] = shuf8(p0, p1);
      p0 = *(const s16x4*)&Bh[bc][lkg]; p1 = *(const s16x4*)&Bh[bc][16 + lkg];
      bfh[f] = shuf8(p0, p1);
      p0 = *(const s16x4*)&Bl[bc][lkg]; p1 = *(const s16x4*)&Bl[bc][16 + lkg];
      bfl[f] = shuf8(p0, p1);
    }
#pragma unroll
    for (int i = 0; i < 4; ++i)
#pragma unroll
      for (int j = 0; j < 4; ++j) {
        acc[i][j] = __builtin_amdgcn_mfma_f32_16x16x32_bf16(afh[i], bfh[j], acc[i][j], 0, 0, 0);
        acc[i][j] = __builtin_amdgcn_mfma_f32_16x16x32_bf16(afh[i], bfl[j], acc[i][j], 0, 0, 0);
        acc[i][j] = __builtin_amdgcn_mfma_f32_16x16x32_bf16(afl[i], bfh[j], acc[i][j], 0, 0, 0);
      }
  }
#pragma unroll
  for (int i = 0; i < 4; ++i) {
    const int row0 = m0 + wr + i * 16 + lkg;
#pragma unroll
    for (int j = 0; j < 4; ++j) {
      const int col = n0 + wc + j * 16 + lrow;
#pragma unroll
      for (int r = 0; r < 4; ++r) {
        float v = acc[i][j][r];
        if (RELU) v = fmaxf(v, 0.f);
        C[(size_t)(row0 + r) * N + col] = v;
      }
    }
  }
}

// ---------------------------------------------------------------------------
// Kernel 3: mid LayerNorm over QKVP=7168, in place on h. One block per row.
__global__ __launch_bounds__(256) void mid_ln_kernel(
    float* __restrict__ h, const float* __restrict__ g, const float* __restrict__ bb) {
  __shared__ float sm[4];
  const int row = blockIdx.x;
  const int t = threadIdx.x;
  float* hr = h + (size_t)row * QKVP;
  float4 r[7];
  float s = 0.f;
#pragma unroll
  for (int j = 0; j < 7; ++j) {
    r[j] = reinterpret_cast<float4*>(hr)[t + j * 256];
    s += r[j].x + r[j].y + r[j].z + r[j].w;
  }
  const float mean = blk_sum256(s, sm) * (1.0f / QKVP);
  float sq = 0.f;
#pragma unroll
  for (int j = 0; j < 7; ++j) {
    r[j].x -= mean; r[j].y -= mean; r[j].z -= mean; r[j].w -= mean;
    sq += r[j].x * r[j].x + r[j].y * r[j].y + r[j].z * r[j].z + r[j].w * r[j].w;
  }
  const float rstd = rsqrtf(blk_sum256(sq, sm) * (1.0f / QKVP) + LN_EPS);
#pragma unroll
  for (int j = 0; j < 7; ++j) {
    const float4 gv = reinterpret_cast<const float4*>(g)[t + j * 256];
    const float4 bv = reinterpret_cast<const float4*>(bb)[t + j * 256];
    float4 o;
    o.x = r[j].x * rstd * gv.x + bv.x;
    o.y = r[j].y * rstd * gv.y + bv.y;
    o.z = r[j].z * rstd * gv.z + bv.z;
    o.w = r[j].w * rstd * gv.w + bv.w;
    reinterpret_cast<float4*>(hr)[t + j * 256] = o;
  }
}

// ---------------------------------------------------------------------------
// Kernel 4: flash attention, split-bf16 MFMA. Grid (L/64, B*H), 256 thr =
// 4 waves; wave w owns q-rows [i0+16w, i0+16w+16).
//
// Swapped-operand structure: S^T = mfma(A=K, B=Q) so the C layout
// (col = i = lane&15, row = j = 4*(lane>>4)+reg) puts each lane's softmax
// row-stats behind 2 shfl_xor (16, 32). P^T stays in registers and feeds
// O^T = mfma(A=V^T, B=P^T) directly (no P LDS round-trip).
//
// k-maps (slot (g = lane>>4, e) -> logical k), same map for A and B of each
// MFMA (mirror-map cancellation, validated by the passing GEMM):
//   QK^T (k = d): d = 32*ks + 8g + e           (contiguous b128 reads)
//   PV   (k = j): j = 32*ks + 16*(e>>2) + 4g + (e&3)
// All operands hi/lo split: 3 MFMAs per product (error ~2^-16, as GEMM).
//
// LDS: K [j][d] stride 72 (b128 16B-aligned, floor conflicts);
//      V^T [d][j] stride 76 (b64 floor conflicts). Total 37.9 KB.
// Writes O back into h's q-slot (block reads exactly the q-rect it
// overwrites; all reads precede all writes).
__global__ __launch_bounds__(256) void attn_kernel(
    float* __restrict__ h, const float* __restrict__ slopes) {
  __shared__ __align__(16) u16 Kh[64][72];
  __shared__ __align__(16) u16 Kl[64][72];
  __shared__ __align__(16) u16 Vh[64][76];  // V^T: [d][j]
  __shared__ __align__(16) u16 Vl[64][76];
  const int it = blockIdx.x, bh = blockIdx.y;
  const int b = bh >> 4, hh = bh & 15;
  const float slope = slopes[hh];
  const int t = threadIdx.x;
  const int lane = t & 63, w = t >> 6;
  const int li = lane & 15;   // i (B-frag col) / j-in-tile (K A-frag) / d-in-tile (V A-frag)
  const int g = lane >> 4;    // k-group
  const int i0 = it * 64;
  const size_t base = (size_t)b * L_SEQ * QKVP;
  const int myrow = i0 + w * 16 + li;  // this lane's global q row

  // ---- Q fragments (hi/lo, 2 k-steps), direct global->reg, map d=32ks+8g+e
  s16x8 qh[2], ql[2];
  {
    const float* qp = h + base + (size_t)myrow * QKVP + hh * 64 + 8 * g;
#pragma unroll
    for (int ks = 0; ks < 2; ++ks) {
      const float4 a0 = *(const float4*)(qp + 32 * ks);
      const float4 a1 = *(const float4*)(qp + 32 * ks + 4);
      s16x4 h0, l0, h1, l1;
      split4(a0, h0, l0);
      split4(a1, h1, l1);
      qh[ks] = shuf8(h0, h1);
      ql[ks] = shuf8(l0, l1);
    }
  }

  float m_run = -INFINITY, l_run = 0.f;
  f32x4 ot[4] = {};  // O^T acc: lane holds rows d = 16*dt+4g+reg, col i = li

  const int sj = t >> 2, sd = (t & 3) * 16;      // K staging map
  const int vj = (t >> 4) * 4, vd = (t & 15) * 4; // V staging map (4x4 blocks)
  const float* kbase = h + base + HID + hh * 64;
  const float* vbase = h + base + 2 * HID + hh * 64;

  for (int jt = 0; jt <= it; ++jt) {
    const int j0 = jt * 64;
    // prefetch tile into regs (no LDS touch before barrier)
    float4 kq[4], vq[4];
#pragma unroll
    for (int q = 0; q < 4; ++q)
      kq[q] = *(const float4*)(kbase + (size_t)(j0 + sj) * QKVP + sd + 4 * q);
#pragma unroll
    for (int r = 0; r < 4; ++r)
      vq[r] = *(const float4*)(vbase + (size_t)(j0 + vj + r) * QKVP + vd);
    __syncthreads();  // previous iteration done reading LDS
    {
      s16x4 h0, l0, h1, l1;
      split4(kq[0], h0, l0); split4(kq[1], h1, l1);
      *(s16x8*)&Kh[sj][sd] = shuf8(h0, h1);
      *(s16x8*)&Kl[sj][sd] = shuf8(l0, l1);
      split4(kq[2], h0, l0); split4(kq[3], h1, l1);
      *(s16x8*)&Kh[sj][sd + 8] = shuf8(h0, h1);
      *(s16x8*)&Kl[sj][sd + 8] = shuf8(l0, l1);
    }
    {
      s16x4 vh4[4], vl4[4];
#pragma unroll
      for (int r = 0; r < 4; ++r) split4(vq[r], vh4[r], vl4[r]);
#pragma unroll
      for (int c = 0; c < 4; ++c) {
        s16x4 hc, lc;
#pragma unroll
        for (int r = 0; r < 4; ++r) { hc[r] = vh4[r][c]; lc[r] = vl4[r][c]; }
        *(s16x4*)&Vh[vd + c][vj] = hc;
        *(s16x4*)&Vl[vd + c][vj] = lc;
      }
    }
    __syncthreads();  // tile ready

    // ---- S^T tiles (4 j-tiles of 16) via 24 MFMAs
    f32x4 sa[4] = {};
#pragma unroll
    for (int j4 = 0; j4 < 4; ++j4) {
      const int jr = j4 * 16 + li;
#pragma unroll
      for (int ks = 0; ks < 2; ++ks) {
        const s16x8 kh = *(const s16x8*)&Kh[jr][ks * 32 + 8 * g];
        const s16x8 kl = *(const s16x8*)&Kl[jr][ks * 32 + 8 * g];
        sa[j4] = __builtin_amdgcn_mfma_f32_16x16x32_bf16(kh, qh[ks], sa[j4], 0, 0, 0);
        sa[j4] = __builtin_amdgcn_mfma_f32_16x16x32_bf16(kh, ql[ks], sa[j4], 0, 0, 0);
        sa[j4] = __builtin_amdgcn_mfma_f32_16x16x32_bf16(kl, qh[ks], sa[j4], 0, 0, 0);
      }
    }
    // ---- scale + alibi + causal mask; online softmax across g-groups
    float pmax = -INFINITY;
#pragma unroll
    for (int j4 = 0; j4 < 4; ++j4)
#pragma unroll
      for (int r = 0; r < 4; ++r) {
        const int jg = j0 + j4 * 16 + 4 * g + r;
        float v = sa[j4][r] * 0.125f + (float)jg * slope;
        if (jg > myrow) v = -1e10f;
        sa[j4][r] = v;
        pmax = fmaxf(pmax, v);
      }
    pmax = fmaxf(pmax, __shfl_xor(pmax, 16));
    pmax = fmaxf(pmax, __shfl_xor(pmax, 32));
    const float m_new = fmaxf(m_run, pmax);
    const float corr = __expf(m_run - m_new);
    m_run = m_new;
    float ls = 0.f;
    s16x8 ph[2], pl[2];
#pragma unroll
    for (int ks = 0; ks < 2; ++ks) {  // P^T frags, map j = 32ks+16*(e>>2)+4g+(e&3)
      f32x4 p0, p1;
#pragma unroll
      for (int r = 0; r < 4; ++r) {
        p0[r] = __expf(sa[2 * ks][r] - m_new);
        p1[r] = __expf(sa[2 * ks + 1][r] - m_new);
        ls += p0[r] + p1[r];
      }
      s16x4 h0, l0, h1, l1;
      split4v(p0, h0, l0);
      split4v(p1, h1, l1);
      ph[ks] = shuf8(h0, h1);
      pl[ks] = shuf8(l0, l1);
    }
    ls += __shfl_xor(ls, 16);
    ls += __shfl_xor(ls, 32);
    l_run = l_run * corr + ls;
#pragma unroll
    for (int dt = 0; dt < 4; ++dt)
#pragma unroll
      for (int r = 0; r < 4; ++r) ot[dt][r] *= corr;
    // ---- O^T += V^T . P^T  (24 MFMAs, P frags already in regs)
#pragma unroll
    for (int dt = 0; dt < 4; ++dt) {
      const int dr = dt * 16 + li;
#pragma unroll
      for (int ks = 0; ks < 2; ++ks) {
        const s16x8 vh8 = shuf8(*(const s16x4*)&Vh[dr][ks * 32 + 4 * g],
                                *(const s16x4*)&Vh[dr][ks * 32 + 16 + 4 * g]);
        const s16x8 vl8 = shuf8(*(const s16x4*)&Vl[dr][ks * 32 + 4 * g],
                                *(const s16x4*)&Vl[dr][ks * 32 + 16 + 4 * g]);
        ot[dt] = __builtin_amdgcn_mfma_f32_16x16x32_bf16(vh8, ph[ks], ot[dt], 0, 0, 0);
        ot[dt] = __builtin_amdgcn_mfma_f32_16x16x32_bf16(vh8, pl[ks], ot[dt], 0, 0, 0);
        ot[dt] = __builtin_amdgcn_mfma_f32_16x16x32_bf16(vl8, ph[ks], ot[dt], 0, 0, 0);
      }
    }
  }
  // ---- epilogue: normalize, write O (un-transposed) into h's q-slot
  const float inv = 1.0f / l_run;
  float* op = h + base + (size_t)myrow * QKVP + hh * 64;
#pragma unroll
  for (int dt = 0; dt < 4; ++dt) {
    float4 ov;
    ov.x = ot[dt][0] * inv;
    ov.y = ot[dt][1] * inv;
    ov.z = ot[dt][2] * inv;
    ov.w = ot[dt][3] * inv;
    *(float4*)(op + dt * 16 + 4 * g) = ov;
  }
}

// ---------------------------------------------------------------------------
// Kernel 5: pg = gelu_exact(p) * roll(p, 1), IN PLACE over h's p-slot.
__device__ __forceinline__ float gelu_exact(float x) {
  return 0.5f * x * (1.0f + erff(x * 0.70710678118654752f));
}
__global__ __launch_bounds__(256) void pg_kernel(float* __restrict__ h) {
  const int row = blockIdx.x;
  float* p = h + (size_t)row * QKVP + 3 * HID;
  const int t = threadIdx.x;
  float4 v[4];
  float pm1[4];
#pragma unroll
  for (int j = 0; j < 4; ++j) {
    const int c4 = t + j * 256;  // 1024 float4 per row
    v[j] = reinterpret_cast<float4*>(p)[c4];
    pm1[j] = p[(c4 * 4 - 1) & 4095];
  }
  __syncthreads();
#pragma unroll
  for (int j = 0; j < 4; ++j) {
    const int c4 = t + j * 256;
    float4 o;
    o.x = gelu_exact(v[j].x) * pm1[j];
    o.y = gelu_exact(v[j].y) * v[j].x;
    o.z = gelu_exact(v[j].z) * v[j].y;
    o.w = gelu_exact(v[j].w) * v[j].z;
    reinterpret_cast<float4*>(p)[c4] = o;
  }
}

// ---------------------------------------------------------------------------
// Kernel 7: final LayerNorm over HID, in place on out.
__global__ __launch_bounds__(256) void ln1024_kernel(
    float* __restrict__ io, const float* __restrict__ g, const float* __restrict__ bb) {
  __shared__ float sm[4];
  const int row = blockIdx.x;
  const int t = threadIdx.x;
  float* xr = io + (size_t)row * HID;
  const float4 v = reinterpret_cast<const float4*>(xr)[t];
  float s = v.x + v.y + v.z + v.w;
  const float mean = blk_sum256(s, sm) * (1.0f / HID);
  const float dx = v.x - mean, dy = v.y - mean, dz = v.z - mean, dw = v.w - mean;
  const float sq = dx * dx + dy * dy + dz * dz + dw * dw;
  const float var = blk_sum256(sq, sm) * (1.0f / HID);
  const float rstd = rsqrtf(var + LN_EPS);
  const float4 gv = reinterpret_cast<const float4*>(g)[t];
  const float4 bv = reinterpret_cast<const float4*>(bb)[t];
  float4 n;
  n.x = dx * rstd * gv.x + bv.x;
  n.y = dy * rstd * gv.y + bv.y;
  n.z = dz * rstd * gv.z + bv.z;
  n.w = dw * rstd * gv.w + bv.w;
  reinterpret_cast<float4*>(xr)[t] = n;
}

// ---------------------------------------------------------------------------
extern "C" void kernel_launch(void* const* d_in, const int* in_sizes, int n_in,
                              void* d_out, int out_size, void* d_ws, size_t ws_size,
                              hipStream_t stream) {
  const float* x      = (const float*)d_in[0];
  const float* in_g   = (const float*)d_in[1];
  const float* in_b   = (const float*)d_in[2];
  const float* W_in   = (const float*)d_in[3];
  const float* mid_g  = (const float*)d_in[4];
  const float* mid_b  = (const float*)d_in[5];
  const float* slopes = (const float*)d_in[6];
  const float* W_out  = (const float*)d_in[7];
  const float* out_g  = (const float*)d_in[8];
  const float* out_b  = (const float*)d_in[9];
  float* out = (float*)d_out;

  // Workspace: h fp32 only = 117,440,512 B (112 MiB).
  // xs (4096x1024 fp32 = out_size) is staged IN d_out: written by ln_shift,
  // consumed by gemm1, dead until gemm2 overwrites d_out with the result.
  float* h  = (float*)d_ws;
  float* xs = out;
  const size_t needed = (size_t)NROWS * QKVP * sizeof(float);
  if (ws_size < needed) return;  // diagnostic: no crash; output stays poisoned

  ln_shift_kernel<<<NROWS, 256, 0, stream>>>(x, in_g, in_b, xs);
  // gemm1: h = relu(xs @ W_in^T)   [4096 x 7168, K=1024]
  gemm_f32_hilo<true, false><<<(NROWS / 128) * (QKVP / 128), 256, 0, stream>>>(
      xs, W_in, h, QKVP, HID, HID, QKVP / 128);
  mid_ln_kernel<<<NROWS, 256, 0, stream>>>(h, mid_g, mid_b);
  attn_kernel<<<dim3(L_SEQ / 64, NB * NH), 256, 0, stream>>>(h, slopes);
  pg_kernel<<<NROWS, 256, 0, stream>>>(h);
  // gemm2: out = [o | pg] @ W_out^T   [4096 x 1024, K=5120, A remapped in h]
  gemm_f32_hilo<false, true><<<(NROWS / 128) * (HID / 128), 256, 0, stream>>>(
      h, W_out, out, HID, VP, QKVP, HID / 128);
  ln1024_kernel<<<NROWS, 256, 0, stream>>>(out, out_g, out_b);
}

// Round 11
// 897.436 us; speedup vs baseline: 1.4096x; 1.0712x over previous
//
#include <hip/hip_runtime.h>
#include <math.h>

// Problem constants (B, L, H, D, EF) = (2, 2048, 16, 64, 4)
#define L_SEQ 2048
#define NB 2
#define NH 16
#define HID 1024
#define QKVP 7168   // HID * 7
#define VP 5120     // HID * 5
#define NROWS 4096  // NB * L_SEQ
#define LN_EPS 1e-5f

typedef unsigned short u16;
using s16x4 = __attribute__((ext_vector_type(4))) short;
using s16x8 = __attribute__((ext_vector_type(8))) short;
using f32x4 = __attribute__((ext_vector_type(4))) float;

// --------------------------- bf16 split helpers ----------------------------
__device__ __forceinline__ u16 f2bf(float f) {  // RNE
  unsigned u = __float_as_uint(f);
  u += 0x7FFFu + ((u >> 16) & 1u);
  return (u16)(u >> 16);
}
__device__ __forceinline__ float bf2f(u16 h) {
  return __uint_as_float((unsigned)h << 16);
}
struct HiLo { short hi, lo; };
__device__ __forceinline__ HiLo split2(float x) {
  HiLo r;
  const u16 h = f2bf(x);
  r.hi = (short)h;
  r.lo = (short)f2bf(x - bf2f(h));
  return r;
}
__device__ __forceinline__ void split4(float4 v, s16x4& h4, s16x4& l4) {
  const HiLo a = split2(v.x), b = split2(v.y), c = split2(v.z), d = split2(v.w);
  h4[0] = a.hi; l4[0] = a.lo;
  h4[1] = b.hi; l4[1] = b.lo;
  h4[2] = c.hi; l4[2] = c.lo;
  h4[3] = d.hi; l4[3] = d.lo;
}
__device__ __forceinline__ void split4v(f32x4 v, s16x4& h4, s16x4& l4) {
  const HiLo a = split2(v[0]), b = split2(v[1]), c = split2(v[2]), d = split2(v[3]);
  h4[0] = a.hi; l4[0] = a.lo;
  h4[1] = b.hi; l4[1] = b.lo;
  h4[2] = c.hi; l4[2] = c.lo;
  h4[3] = d.hi; l4[3] = d.lo;
}
__device__ __forceinline__ s16x8 shuf8(s16x4 a, s16x4 b) {
  return __builtin_shufflevector(a, b, 0, 1, 2, 3, 4, 5, 6, 7);
}
__device__ __forceinline__ float rec2(s16x4 hv, s16x4 lv, int i) {
  return bf2f((u16)hv[i]) + bf2f((u16)lv[i]);
}

// ---------------------------------------------------------------------------
// Block-wide (256-thread) sum reduction. Returns full sum to every thread.
__device__ __forceinline__ float blk_sum256(float v, float* sm) {
#pragma unroll
  for (int m = 32; m >= 1; m >>= 1) v += __shfl_xor(v, m, 64);
  __syncthreads();
  if ((threadIdx.x & 63) == 0) sm[threadIdx.x >> 6] = v;
  __syncthreads();
  return sm[0] + sm[1] + sm[2] + sm[3];
}

// ---------------------------------------------------------------------------
// Kernel 1: input LayerNorm over HID + channel-group seq-shift (scatter),
// writing bf16 hi/lo split. Zero-fills shift boundary rows (dest poisoned).
__global__ __launch_bounds__(256) void ln_shift_kernel(
    const float* __restrict__ x, const float* __restrict__ g,
    const float* __restrict__ bb, u16* __restrict__ xh, u16* __restrict__ xl) {
  __shared__ float sm[4];
  const int row = blockIdx.x;  // b*L + l
  const int l = row & (L_SEQ - 1);
  const int t = threadIdx.x;
  const float4 v = reinterpret_cast<const float4*>(x + (size_t)row * HID)[t];
  float s = v.x + v.y + v.z + v.w;
  const float mean = blk_sum256(s, sm) * (1.0f / HID);
  const float dx = v.x - mean, dy = v.y - mean, dz = v.z - mean, dw = v.w - mean;
  const float sq = dx * dx + dy * dy + dz * dz + dw * dw;
  const float var = blk_sum256(sq, sm) * (1.0f / HID);
  const float rstd = rsqrtf(var + LN_EPS);
  const float4 gv = reinterpret_cast<const float4*>(g)[t];
  const float4 bv = reinterpret_cast<const float4*>(bb)[t];
  float4 n;
  n.x = dx * rstd * gv.x + bv.x;
  n.y = dy * rstd * gv.y + bv.y;
  n.z = dz * rstd * gv.z + bv.z;
  n.w = dw * rstd * gv.w + bv.w;
  s16x4 h4, l4;
  split4(n, h4, l4);
  const s16x4 z4 = {0, 0, 0, 0};
  const int c0 = t * 4;
  if (c0 < 128) {
    if (l + 1 < L_SEQ) {
      *(s16x4*)(xh + (size_t)(row + 1) * HID + c0) = h4;
      *(s16x4*)(xl + (size_t)(row + 1) * HID + c0) = l4;
    }
    if (l == 0) {
      *(s16x4*)(xh + (size_t)row * HID + c0) = z4;
      *(s16x4*)(xl + (size_t)row * HID + c0) = z4;
    }
  } else if (c0 < 256) {
    if (l + 3 < L_SEQ) {
      *(s16x4*)(xh + (size_t)(row + 3) * HID + c0) = h4;
      *(s16x4*)(xl + (size_t)(row + 3) * HID + c0) = l4;
    }
    if (l < 3) {
      *(s16x4*)(xh + (size_t)row * HID + c0) = z4;
      *(s16x4*)(xl + (size_t)row * HID + c0) = z4;
    }
  } else {
    *(s16x4*)(xh + (size_t)row * HID + c0) = h4;
    *(s16x4*)(xl + (size_t)row * HID + c0) = l4;
  }
}

// ---------------------------------------------------------------------------
// Split-bf16 NT GEMM: C[m][n] = sum_k A[m][k]*Bw[n][k].
// A is PRE-SPLIT bf16 hi/lo in global; fragments load DIRECTLY global->reg
// (no LDS for A; xs/h slices are L2/L3-resident). B (weights, fp32) staged
// through LDS with in-loop split (read ~32x, acceptable).
// Tile 128x128x32, 4 waves (2x2) x 64x64. Contiguous k-map: slot(g,e) ->
// k = k0+8g+e for BOTH operands (mirror-map cancellation; map already
// validated by round-9 attention QK^T). Triple product hi*hi+hi*lo+lo*hi.
// SPLIT_OUT epilogue writes bf16 hi/lo (for h); else fp32.
template <bool RELU, bool A_REMAP, bool SPLIT_OUT>
__global__ __launch_bounds__(256, 3) void gemm_asplit(
    const u16* __restrict__ Ahi, const u16* __restrict__ Alo,
    const float* __restrict__ Bw, float* __restrict__ C,
    u16* __restrict__ Chi, u16* __restrict__ Clo,
    int N, int K, int lda, int nbx) {
  __shared__ __align__(16) u16 Bh[128][40];
  __shared__ __align__(16) u16 Bl[128][40];

  // bijective XCD swizzle (gridDim.x % 8 == 0 at both call sites)
  const int cpx = (int)gridDim.x >> 3;
  const int b0 = blockIdx.x;
  const int swz = (b0 & 7) * cpx + (b0 >> 3);
  const int bx = swz % nbx, by = swz / nbx;
  const int m0 = by * 128, n0 = bx * 128;

  const int t = threadIdx.x;
  const int lane = t & 63, w = t >> 6;
  const int wr = (w >> 1) * 64, wc = (w & 1) * 64;  // wave sub-tile origin
  const int li = lane & 15;
  const int g = lane >> 4;

  f32x4 acc[4][4] = {};

  const int sr = t >> 1;        // B staging row 0..127
  const int sk = (t & 1) * 16;  // B staging k base {0,16}

  size_t arow[4];
#pragma unroll
  for (int f = 0; f < 4; ++f)
    arow[f] = (size_t)(m0 + wr + f * 16 + li) * lda;

  for (int k0 = 0; k0 < K; k0 += 32) {
    // B global loads (fp32)
    const float* bp = Bw + (size_t)(n0 + sr) * K + sk + k0;
    const float4 bv0 = *(const float4*)(bp);
    const float4 bv1 = *(const float4*)(bp + 4);
    const float4 bv2 = *(const float4*)(bp + 8);
    const float4 bv3 = *(const float4*)(bp + 12);
    // A fragments: direct global (pre-split), k-map k = k0+8g+e
    int ak = k0 + 8 * g;
    if (A_REMAP && ak >= 1024) ak += 2048;  // skip k,v slots of h
    s16x8 afh[4], afl[4];
#pragma unroll
    for (int f = 0; f < 4; ++f) {
      afh[f] = *(const s16x8*)(Ahi + arow[f] + ak);
      afl[f] = *(const s16x8*)(Alo + arow[f] + ak);
    }
    __syncthreads();  // previous iteration done reading LDS
    {
      s16x4 h0, l0, h1, l1;
      split4(bv0, h0, l0); split4(bv1, h1, l1);
      *(s16x8*)&Bh[sr][sk] = shuf8(h0, h1);
      *(s16x8*)&Bl[sr][sk] = shuf8(l0, l1);
      split4(bv2, h0, l0); split4(bv3, h1, l1);
      *(s16x8*)&Bh[sr][sk + 8] = shuf8(h0, h1);
      *(s16x8*)&Bl[sr][sk + 8] = shuf8(l0, l1);
    }
    __syncthreads();  // tile ready

    s16x8 bfh[4], bfl[4];
#pragma unroll
    for (int f = 0; f < 4; ++f) {
      bfh[f] = *(const s16x8*)&Bh[wc + f * 16 + li][8 * g];
      bfl[f] = *(const s16x8*)&Bl[wc + f * 16 + li][8 * g];
    }
#pragma unroll
    for (int i = 0; i < 4; ++i)
#pragma unroll
      for (int j = 0; j < 4; ++j) {
        acc[i][j] = __builtin_amdgcn_mfma_f32_16x16x32_bf16(afh[i], bfh[j], acc[i][j], 0, 0, 0);
        acc[i][j] = __builtin_amdgcn_mfma_f32_16x16x32_bf16(afh[i], bfl[j], acc[i][j], 0, 0, 0);
        acc[i][j] = __builtin_amdgcn_mfma_f32_16x16x32_bf16(afl[i], bfh[j], acc[i][j], 0, 0, 0);
      }
  }
  // Epilogue. D mapping (m89-verified): col = lane&15, row = 4*(lane>>4)+reg.
#pragma unroll
  for (int i = 0; i < 4; ++i) {
    const int row0 = m0 + wr + i * 16 + 4 * g;
#pragma unroll
    for (int j = 0; j < 4; ++j) {
      const int col = n0 + wc + j * 16 + li;
#pragma unroll
      for (int r = 0; r < 4; ++r) {
        float v = acc[i][j][r];
        if (RELU) v = fmaxf(v, 0.f);
        const size_t off = (size_t)(row0 + r) * N + col;
        if constexpr (SPLIT_OUT) {
          const HiLo sp = split2(v);
          Chi[off] = (u16)sp.hi;
          Clo[off] = (u16)sp.lo;
        } else {
          C[off] = v;
        }
      }
    }
  }
}

// ---------------------------------------------------------------------------
// Kernel 3: mid LayerNorm over QKVP=7168, in place on split h.
__global__ __launch_bounds__(256) void mid_ln_kernel(
    u16* __restrict__ hh_, u16* __restrict__ hl_,
    const float* __restrict__ g, const float* __restrict__ bb) {
  __shared__ float sm[4];
  const int row = blockIdx.x;
  const int t = threadIdx.x;
  u16* hr = hh_ + (size_t)row * QKVP;
  u16* lr = hl_ + (size_t)row * QKVP;
  float4 r[7];
  float s = 0.f;
#pragma unroll
  for (int j = 0; j < 7; ++j) {
    const int c = 4 * t + j * 1024;
    const s16x4 hv = *(const s16x4*)(hr + c);
    const s16x4 lv = *(const s16x4*)(lr + c);
    r[j].x = rec2(hv, lv, 0);
    r[j].y = rec2(hv, lv, 1);
    r[j].z = rec2(hv, lv, 2);
    r[j].w = rec2(hv, lv, 3);
    s += r[j].x + r[j].y + r[j].z + r[j].w;
  }
  const float mean = blk_sum256(s, sm) * (1.0f / QKVP);
  float sq = 0.f;
#pragma unroll
  for (int j = 0; j < 7; ++j) {
    r[j].x -= mean; r[j].y -= mean; r[j].z -= mean; r[j].w -= mean;
    sq += r[j].x * r[j].x + r[j].y * r[j].y + r[j].z * r[j].z + r[j].w * r[j].w;
  }
  const float rstd = rsqrtf(blk_sum256(sq, sm) * (1.0f / QKVP) + LN_EPS);
#pragma unroll
  for (int j = 0; j < 7; ++j) {
    const int c = 4 * t + j * 1024;
    const float4 gv = *(const float4*)(g + c);
    const float4 bv = *(const float4*)(bb + c);
    float4 o;
    o.x = r[j].x * rstd * gv.x + bv.x;
    o.y = r[j].y * rstd * gv.y + bv.y;
    o.z = r[j].z * rstd * gv.z + bv.z;
    o.w = r[j].w * rstd * gv.w + bv.w;
    s16x4 h4, l4;
    split4(o, h4, l4);
    *(s16x4*)(hr + c) = h4;
    *(s16x4*)(lr + c) = l4;
  }
}

// ---------------------------------------------------------------------------
// Kernel 4: flash attention, split-bf16 MFMA on pre-split h (no in-kernel
// split for Q/K/V — direct u16 staging). Structure identical to the
// round-9-validated kernel. Writes O (split) back into h's q-slot.
__global__ __launch_bounds__(256) void attn_kernel(
    u16* __restrict__ hh_, u16* __restrict__ hl_,
    const float* __restrict__ slopes) {
  __shared__ __align__(16) u16 Kh[64][72];
  __shared__ __align__(16) u16 Kl[64][72];
  __shared__ __align__(16) u16 Vh[64][76];  // V^T: [d][j]
  __shared__ __align__(16) u16 Vl[64][76];
  const int it = blockIdx.x, bh = blockIdx.y;
  const int b = bh >> 4, hh = bh & 15;
  const float slope = slopes[hh];
  const int t = threadIdx.x;
  const int lane = t & 63, w = t >> 6;
  const int li = lane & 15;
  const int g = lane >> 4;
  const int i0 = it * 64;
  const size_t base = (size_t)b * L_SEQ * QKVP;
  const int myrow = i0 + w * 16 + li;

  // Q fragments: direct loads of pre-split data, map d = 32ks+8g+e
  s16x8 qh[2], ql[2];
  {
    const u16* qph = hh_ + base + (size_t)myrow * QKVP + hh * 64 + 8 * g;
    const u16* qpl = hl_ + base + (size_t)myrow * QKVP + hh * 64 + 8 * g;
#pragma unroll
    for (int ks = 0; ks < 2; ++ks) {
      qh[ks] = *(const s16x8*)(qph + 32 * ks);
      ql[ks] = *(const s16x8*)(qpl + 32 * ks);
    }
  }

  float m_run = -INFINITY, l_run = 0.f;
  f32x4 ot[4] = {};

  const int sj = t >> 2, sd = (t & 3) * 16;
  const int vj = (t >> 4) * 4, vd = (t & 15) * 4;
  const u16* kbh = hh_ + base + HID + hh * 64;
  const u16* kbl = hl_ + base + HID + hh * 64;
  const u16* vbh = hh_ + base + 2 * HID + hh * 64;
  const u16* vbl = hl_ + base + 2 * HID + hh * 64;

  for (int jt = 0; jt <= it; ++jt) {
    const int j0 = jt * 64;
    // prefetch to regs (no LDS touch before barrier)
    const size_t ko = (size_t)(j0 + sj) * QKVP + sd;
    const s16x8 k0h = *(const s16x8*)(kbh + ko);
    const s16x8 k1h = *(const s16x8*)(kbh + ko + 8);
    const s16x8 k0l = *(const s16x8*)(kbl + ko);
    const s16x8 k1l = *(const s16x8*)(kbl + ko + 8);
    s16x4 vh4[4], vl4[4];
#pragma unroll
    for (int r = 0; r < 4; ++r) {
      const size_t vo = (size_t)(j0 + vj + r) * QKVP + vd;
      vh4[r] = *(const s16x4*)(vbh + vo);
      vl4[r] = *(const s16x4*)(vbl + vo);
    }
    __syncthreads();  // previous iteration done reading LDS
    *(s16x8*)&Kh[sj][sd] = k0h;
    *(s16x8*)&Kh[sj][sd + 8] = k1h;
    *(s16x8*)&Kl[sj][sd] = k0l;
    *(s16x8*)&Kl[sj][sd + 8] = k1l;
#pragma unroll
    for (int c = 0; c < 4; ++c) {
      s16x4 hc, lc;
#pragma unroll
      for (int r = 0; r < 4; ++r) { hc[r] = vh4[r][c]; lc[r] = vl4[r][c]; }
      *(s16x4*)&Vh[vd + c][vj] = hc;
      *(s16x4*)&Vl[vd + c][vj] = lc;
    }
    __syncthreads();  // tile ready

    // S^T tiles via 24 MFMAs
    f32x4 sa[4] = {};
#pragma unroll
    for (int j4 = 0; j4 < 4; ++j4) {
      const int jr = j4 * 16 + li;
#pragma unroll
      for (int ks = 0; ks < 2; ++ks) {
        const s16x8 kh = *(const s16x8*)&Kh[jr][ks * 32 + 8 * g];
        const s16x8 kl = *(const s16x8*)&Kl[jr][ks * 32 + 8 * g];
        sa[j4] = __builtin_amdgcn_mfma_f32_16x16x32_bf16(kh, qh[ks], sa[j4], 0, 0, 0);
        sa[j4] = __builtin_amdgcn_mfma_f32_16x16x32_bf16(kh, ql[ks], sa[j4], 0, 0, 0);
        sa[j4] = __builtin_amdgcn_mfma_f32_16x16x32_bf16(kl, qh[ks], sa[j4], 0, 0, 0);
      }
    }
    // scale + alibi + causal; online softmax across g-groups
    float pmax = -INFINITY;
#pragma unroll
    for (int j4 = 0; j4 < 4; ++j4)
#pragma unroll
      for (int r = 0; r < 4; ++r) {
        const int jg = j0 + j4 * 16 + 4 * g + r;
        float v = sa[j4][r] * 0.125f + (float)jg * slope;
        if (jg > myrow) v = -1e10f;
        sa[j4][r] = v;
        pmax = fmaxf(pmax, v);
      }
    pmax = fmaxf(pmax, __shfl_xor(pmax, 16));
    pmax = fmaxf(pmax, __shfl_xor(pmax, 32));
    const float m_new = fmaxf(m_run, pmax);
    const float corr = __expf(m_run - m_new);
    m_run = m_new;
    float ls = 0.f;
    s16x8 ph[2], pl[2];
#pragma unroll
    for (int ks = 0; ks < 2; ++ks) {  // P^T frags, map j = 32ks+16*(e>>2)+4g+(e&3)
      f32x4 p0, p1;
#pragma unroll
      for (int r = 0; r < 4; ++r) {
        p0[r] = __expf(sa[2 * ks][r] - m_new);
        p1[r] = __expf(sa[2 * ks + 1][r] - m_new);
        ls += p0[r] + p1[r];
      }
      s16x4 h0, l0, h1, l1;
      split4v(p0, h0, l0);
      split4v(p1, h1, l1);
      ph[ks] = shuf8(h0, h1);
      pl[ks] = shuf8(l0, l1);
    }
    ls += __shfl_xor(ls, 16);
    ls += __shfl_xor(ls, 32);
    l_run = l_run * corr + ls;
#pragma unroll
    for (int dt = 0; dt < 4; ++dt)
#pragma unroll
      for (int r = 0; r < 4; ++r) ot[dt][r] *= corr;
    // O^T += V^T . P^T
#pragma unroll
    for (int dt = 0; dt < 4; ++dt) {
      const int dr = dt * 16 + li;
#pragma unroll
      for (int ks = 0; ks < 2; ++ks) {
        const s16x8 vh8 = shuf8(*(const s16x4*)&Vh[dr][ks * 32 + 4 * g],
                                *(const s16x4*)&Vh[dr][ks * 32 + 16 + 4 * g]);
        const s16x8 vl8 = shuf8(*(const s16x4*)&Vl[dr][ks * 32 + 4 * g],
                                *(const s16x4*)&Vl[dr][ks * 32 + 16 + 4 * g]);
        ot[dt] = __builtin_amdgcn_mfma_f32_16x16x32_bf16(vh8, ph[ks], ot[dt], 0, 0, 0);
        ot[dt] = __builtin_amdgcn_mfma_f32_16x16x32_bf16(vh8, pl[ks], ot[dt], 0, 0, 0);
        ot[dt] = __builtin_amdgcn_mfma_f32_16x16x32_bf16(vl8, ph[ks], ot[dt], 0, 0, 0);
      }
    }
  }
  // epilogue: normalize, write split O into h's q-slot
  const float inv = 1.0f / l_run;
  u16* oph = hh_ + base + (size_t)myrow * QKVP + hh * 64;
  u16* opl = hl_ + base + (size_t)myrow * QKVP + hh * 64;
#pragma unroll
  for (int dt = 0; dt < 4; ++dt) {
    f32x4 ov;
    ov[0] = ot[dt][0] * inv;
    ov[1] = ot[dt][1] * inv;
    ov[2] = ot[dt][2] * inv;
    ov[3] = ot[dt][3] * inv;
    s16x4 h4, l4;
    split4v(ov, h4, l4);
    *(s16x4*)(oph + dt * 16 + 4 * g) = h4;
    *(s16x4*)(opl + dt * 16 + 4 * g) = l4;
  }
}

// ---------------------------------------------------------------------------
// Kernel 5: pg = gelu_exact(p) * roll(p, 1), in place over split h's p-slot.
__device__ __forceinline__ float gelu_exact(float x) {
  return 0.5f * x * (1.0f + erff(x * 0.70710678118654752f));
}
__global__ __launch_bounds__(256) void pg_kernel(
    u16* __restrict__ hh_, u16* __restrict__ hl_) {
  const int row = blockIdx.x;
  u16* ph = hh_ + (size_t)row * QKVP + 3 * HID;
  u16* pl = hl_ + (size_t)row * QKVP + 3 * HID;
  const int t = threadIdx.x;
  float4 v[4];
  float pm1[4];
#pragma unroll
  for (int j = 0; j < 4; ++j) {
    const int c0 = 4 * (t + j * 256);
    const s16x4 hv = *(const s16x4*)(ph + c0);
    const s16x4 lv = *(const s16x4*)(pl + c0);
    v[j].x = rec2(hv, lv, 0);
    v[j].y = rec2(hv, lv, 1);
    v[j].z = rec2(hv, lv, 2);
    v[j].w = rec2(hv, lv, 3);
    const int cm = (c0 - 1) & 4095;
    pm1[j] = bf2f(ph[cm]) + bf2f(pl[cm]);
  }
  __syncthreads();
#pragma unroll
  for (int j = 0; j < 4; ++j) {
    const int c0 = 4 * (t + j * 256);
    float4 o;
    o.x = gelu_exact(v[j].x) * pm1[j];
    o.y = gelu_exact(v[j].y) * v[j].x;
    o.z = gelu_exact(v[j].z) * v[j].y;
    o.w = gelu_exact(v[j].w) * v[j].z;
    s16x4 h4, l4;
    split4(o, h4, l4);
    *(s16x4*)(ph + c0) = h4;
    *(s16x4*)(pl + c0) = l4;
  }
}

// ---------------------------------------------------------------------------
// Kernel 7: final LayerNorm over HID, in place on out (fp32).
__global__ __launch_bounds__(256) void ln1024_kernel(
    float* __restrict__ io, const float* __restrict__ g, const float* __restrict__ bb) {
  __shared__ float sm[4];
  const int row = blockIdx.x;
  const int t = threadIdx.x;
  float* xr = io + (size_t)row * HID;
  const float4 v = reinterpret_cast<const float4*>(xr)[t];
  float s = v.x + v.y + v.z + v.w;
  const float mean = blk_sum256(s, sm) * (1.0f / HID);
  const float dx = v.x - mean, dy = v.y - mean, dz = v.z - mean, dw = v.w - mean;
  const float sq = dx * dx + dy * dy + dz * dz + dw * dw;
  const float var = blk_sum256(sq, sm) * (1.0f / HID);
  const float rstd = rsqrtf(var + LN_EPS);
  const float4 gv = reinterpret_cast<const float4*>(g)[t];
  const float4 bv = reinterpret_cast<const float4*>(bb)[t];
  float4 n;
  n.x = dx * rstd * gv.x + bv.x;
  n.y = dy * rstd * gv.y + bv.y;
  n.z = dz * rstd * gv.z + bv.z;
  n.w = dw * rstd * gv.w + bv.w;
  reinterpret_cast<float4*>(xr)[t] = n;
}

// ---------------------------------------------------------------------------
extern "C" void kernel_launch(void* const* d_in, const int* in_sizes, int n_in,
                              void* d_out, int out_size, void* d_ws, size_t ws_size,
                              hipStream_t stream) {
  const float* x      = (const float*)d_in[0];
  const float* in_g   = (const float*)d_in[1];
  const float* in_b   = (const float*)d_in[2];
  const float* W_in   = (const float*)d_in[3];
  const float* mid_g  = (const float*)d_in[4];
  const float* mid_b  = (const float*)d_in[5];
  const float* slopes = (const float*)d_in[6];
  const float* W_out  = (const float*)d_in[7];
  const float* out_g  = (const float*)d_in[8];
  const float* out_b  = (const float*)d_in[9];
  float* out = (float*)d_out;

  // Workspace: h as bf16 hi/lo pair = 2 x 4096x7168x2 B = 117,440,512 B
  // (identical 112 MiB footprint to the fp32 h that ran in rounds 7/9).
  // xs hi/lo (2 x 4096x1024x2 B = 16.8 MB) lives in d_out: written by
  // ln_shift, consumed by gemm1, dead until gemm2 writes the fp32 result.
  u16* h_hi = (u16*)d_ws;
  u16* h_lo = h_hi + (size_t)NROWS * QKVP;
  u16* xs_hi = (u16*)out;
  u16* xs_lo = xs_hi + (size_t)NROWS * HID;
  const size_t needed = (size_t)NROWS * QKVP * 4;  // 2 arrays x 2 B
  if (ws_size < needed) return;  // diagnostic: no crash; output stays poisoned

  ln_shift_kernel<<<NROWS, 256, 0, stream>>>(x, in_g, in_b, xs_hi, xs_lo);
  // gemm1: h(split) = relu(xs @ W_in^T)   [4096 x 7168, K=1024]
  gemm_asplit<true, false, true><<<(NROWS / 128) * (QKVP / 128), 256, 0, stream>>>(
      xs_hi, xs_lo, W_in, nullptr, h_hi, h_lo, QKVP, HID, HID, QKVP / 128);
  mid_ln_kernel<<<NROWS, 256, 0, stream>>>(h_hi, h_lo, mid_g, mid_b);
  attn_kernel<<<dim3(L_SEQ / 64, NB * NH), 256, 0, stream>>>(h_hi, h_lo, slopes);
  pg_kernel<<<NROWS, 256, 0, stream>>>(h_hi, h_lo);
  // gemm2: out = [o | pg] @ W_out^T   [4096 x 1024, K=5120, A remapped in h]
  gemm_asplit<false, true, false><<<(NROWS / 128) * (HID / 128), 256, 0, stream>>>(
      h_hi, h_lo, W_out, out, nullptr, nullptr, HID, VP, QKVP, HID / 128);
  ln1024_kernel<<<NROWS, 256, 0, stream>>>(out, out_g, out_b);
}